// Round 3
// baseline (193.120 us; speedup 1.0000x reference)
//
#include <hip/hip_runtime.h>

#define DD 512   // feature dim
#define H1 256   // hidden 1
#define H2 128   // hidden 2
#define CC 20    // real classes
#define CP 24    // padded classes (4 groups x 6)

// workspace float offsets
#define OFF_SUMF 0
#define OFF_B1C  (CC*DD)                 // 10240
#define OFF_H10  (OFF_B1C + CP*H1)       // 16384
#define OFF_PRE  (OFF_H10 + H1)          // 16640
#define OFF_ST   (OFF_PRE + CC*H2)       // 19200
#define NSTAT    (1 + 4*CP)              // 97

// ---------------- prep1: class sums + degree stats ----------------
__global__ __launch_bounds__(256) void k_prep1(
    const float* __restrict__ Sf, const int* __restrict__ labels, int S,
    float* __restrict__ SumF, float* __restrict__ stats) {
  __shared__ int lab[128];
  int tid = threadIdx.x;
  if (tid < S) lab[tid] = labels[tid];
  __syncthreads();
  int b = blockIdx.x;
  if (b < CC) {
    for (int d = tid; d < DD; d += 256) {
      float acc = 0.f;
      for (int j = 0; j < S; ++j)
        if (lab[j] == b) acc += Sf[j * DD + d];
      SumF[b * DD + d] = acc;
    }
  } else if (tid < CP) {
    int cnt = 0;
    for (int j = 0; j < S; ++j) if (lab[j] == tid) cnt++;
    float deg = 1.f + (float)cnt;
    float dis  = rsqrtf(deg + 1e-6f);
    float dis0 = rsqrtf((float)S + 1e-6f);
    stats[1 + tid]          = dis;                       // dis_c
    stats[1 + CP + tid]     = dis0 * dis;                // alpha_c
    stats[1 + 2*CP + tid]   = dis * dis * (float)cnt;    // beta_c  (0 for pad)
    stats[1 + 3*CP + tid]   = dis * (float)cnt;          // gamma_c (0 for pad)
    if (tid == 0) stats[0] = dis0;
  }
}

// ---------------- prep2: B1c rows, pad rows, h1_0, pre_ck ----------------
__global__ __launch_bounds__(256) void k_prep2(
    const float* __restrict__ SumF, const float* __restrict__ W1,
    const float* __restrict__ b1, const float* __restrict__ W2,
    const float* __restrict__ b2, const float* __restrict__ stats,
    float* __restrict__ B1c, float* __restrict__ h10, float* __restrict__ pre) {
  int b = blockIdx.x, tid = threadIdx.x;
  if (b < CC) {
    float dis = stats[1 + b];
    float sc = dis * dis;
    float acc = 0.f;
#pragma unroll 4
    for (int d = 0; d < DD; ++d) acc += SumF[b * DD + d] * W1[d * H1 + tid];
    B1c[b * H1 + tid] = b1[tid] + sc * acc;
  } else if (b < CP) {
    B1c[b * H1 + tid] = 0.f;
  } else {
    __shared__ float row0[DD];
    __shared__ float h10l[H1];
    float dis0 = stats[0];
    for (int d = tid; d < DD; d += 256) {
      float acc = 0.f;
#pragma unroll
      for (int c = 0; c < CC; ++c) acc += stats[1 + c] * SumF[c * DD + d];
      row0[d] = dis0 * acc;
    }
    __syncthreads();
    float acc = 0.f;
#pragma unroll 4
    for (int d = 0; d < DD; ++d) acc += row0[d] * W1[d * H1 + tid];
    float h = fmaxf(b1[tid] + acc, 0.f);
    h10l[tid] = h;
    h10[tid] = h;
    __syncthreads();
    if (tid < H2) {
      float g = 0.f;
#pragma unroll 4
      for (int j = 0; j < H1; ++j) g += h10l[j] * W2[j * H2 + tid];
      float bb = b2[tid];
#pragma unroll
      for (int c = 0; c < CC; ++c)
        pre[c * H2 + tid] = dis0 * stats[1 + c] * g + bb;
    }
  }
}

// ---------------- k_query: 2 queries per block, fused u-phase ----------------
__global__ __launch_bounds__(256, 2) void k_query(
    const float* __restrict__ qf, const float* __restrict__ W1,
    const float* __restrict__ W2, const float* __restrict__ b2,
    const float* __restrict__ B1c, const float* __restrict__ pre_ck,
    const float* __restrict__ stats, float* __restrict__ out, int Q) {
  __shared__ __align__(16) float h1[2][CP][H1];        // 48 KB
  __shared__ __align__(16) float u_lds[2][H1];         // 2 KB
  __shared__ __align__(16) float proto[2][CC][H2 + 4]; // 21.1 KB
  __shared__ __align__(16) float psum[2][4][H2];       // 4 KB
  __shared__ float qe[2][H2];
  __shared__ float stc[NSTAT];

  int tid = threadIdx.x;
  int q0 = blockIdx.x * 2;
  bool has2 = (q0 + 1 < Q);

  if (tid < NSTAT) stc[tid] = stats[tid];

  // ---- phase 0: u[q][tid] = qf[q] @ W1[:, tid] (coalesced W1, s_load qf) ----
  {
    float a0 = 0.f, a1 = 0.f;
    const float* qp = qf + (size_t)q0 * DD;
#pragma unroll 8
    for (int d = 0; d < DD; ++d) {
      float w = W1[d * H1 + tid];
      a0 = fmaf(qp[d], w, a0);
      if (has2) a1 = fmaf(qp[DD + d], w, a1);
    }
    u_lds[0][tid] = a0;
    u_lds[1][tid] = a1;
  }
  __syncthreads();

  // ---- h1[q][c][j] = relu(alpha_c * u[q][j] + B1c[c][j]) ----
#pragma unroll
  for (int e = tid; e < 2 * CP * H1; e += 256) {
    int qq = e / (CP * H1);
    int r  = e - qq * (CP * H1);
    int c  = r >> 8, j = r & (H1 - 1);
    h1[qq][c][j] = fmaxf(stc[1 + CP + c] * u_lds[qq][j] + B1c[r], 0.f);
  }
  __syncthreads();

  // ---- P-GEMM: thread = (q, group, kq); 6 classes x 4 k each ----
  int q  = tid >> 7;          // 0/1
  int g  = (tid >> 5) & 3;    // class group
  int kq = tid & 31;          // k quad
  int cb = g * 6;
  int k4 = kq * 4;

  float acc[6][4];
#pragma unroll
  for (int i = 0; i < 6; ++i)
#pragma unroll
    for (int kk = 0; kk < 4; ++kk) acc[i][kk] = 0.f;

  const float4* __restrict__ W2v = (const float4*)W2;
  float4 wc0 = W2v[0 * 32 + kq];
  float4 wc1 = W2v[1 * 32 + kq];
  float4 wc2 = W2v[2 * 32 + kq];
  float4 wc3 = W2v[3 * 32 + kq];

#pragma unroll 2
  for (int j0 = 0; j0 < H1; j0 += 4) {
    // prefetch next j-step of W2
    float4 wn0, wn1, wn2, wn3;
    int jn = j0 + 4;
    if (jn < H1) {
      wn0 = W2v[(jn + 0) * 32 + kq];
      wn1 = W2v[(jn + 1) * 32 + kq];
      wn2 = W2v[(jn + 2) * 32 + kq];
      wn3 = W2v[(jn + 3) * 32 + kq];
    }
    float4 hh[6];
#pragma unroll
    for (int i = 0; i < 6; ++i)
      hh[i] = *(const float4*)&h1[q][cb + i][j0];   // broadcast, 2 addrs/wave

    const float4 wrow[4] = {wc0, wc1, wc2, wc3};
#pragma unroll
    for (int jj = 0; jj < 4; ++jj) {
      float w0 = ((const float*)&wrow[jj])[0];
      float w1 = ((const float*)&wrow[jj])[1];
      float w2 = ((const float*)&wrow[jj])[2];
      float w3 = ((const float*)&wrow[jj])[3];
#pragma unroll
      for (int i = 0; i < 6; ++i) {
        float h = ((const float*)&hh[i])[jj];
        acc[i][0] = fmaf(h, w0, acc[i][0]);
        acc[i][1] = fmaf(h, w1, acc[i][1]);
        acc[i][2] = fmaf(h, w2, acc[i][2]);
        acc[i][3] = fmaf(h, w3, acc[i][3]);
      }
    }
    wc0 = wn0; wc1 = wn1; wc2 = wn2; wc3 = wn3;
  }

  // ---- epilogue: protos + gamma-weighted partial sums ----
  {
    __align__(16) float part[4] = {0.f, 0.f, 0.f, 0.f};
#pragma unroll
    for (int i = 0; i < 6; ++i) {
      int c = cb + i;
      float gam = stc[1 + 3 * CP + c];   // 0 for pad classes
#pragma unroll
      for (int kk = 0; kk < 4; ++kk) part[kk] += gam * acc[i][kk];
      if (c < CC) {
        float bet = stc[1 + 2 * CP + c];
        float4 pre = *(const float4*)&pre_ck[c * H2 + k4];
        float4 pr;
        pr.x = fmaxf(pre.x + bet * acc[i][0], 0.f);
        pr.y = fmaxf(pre.y + bet * acc[i][1], 0.f);
        pr.z = fmaxf(pre.z + bet * acc[i][2], 0.f);
        pr.w = fmaxf(pre.w + bet * acc[i][3], 0.f);
        *(float4*)&proto[q][c][k4] = pr;
      }
    }
    *(float4*)&psum[q][g][k4] = *(const float4*)part;
  }
  __syncthreads();

  // ---- qe[q][k] ----
  {
    int qq = tid >> 7, k = tid & (H2 - 1);
    float s = psum[qq][0][k] + psum[qq][1][k] + psum[qq][2][k] + psum[qq][3][k];
    qe[qq][k] = fmaxf(stc[0] * s + b2[k], 0.f);
  }
  __syncthreads();

  // ---- cosine: per query 128 threads, 4-lane groups per class ----
  {
    int qq = tid >> 7, t = tid & 127;
    int cls = t >> 2, l = t & 3;
    if (cls < CC && (qq == 0 || has2)) {
      float num = 0.f, pn = 0.f, qn = 0.f;
#pragma unroll
      for (int i = 0; i < 32; ++i) {
        int k = l + 4 * i;
        float e = qe[qq][k], p = proto[qq][cls][k];
        num = fmaf(e, p, num); pn = fmaf(p, p, pn); qn = fmaf(e, e, qn);
      }
      num += __shfl_xor(num, 1); pn += __shfl_xor(pn, 1); qn += __shfl_xor(qn, 1);
      num += __shfl_xor(num, 2); pn += __shfl_xor(pn, 2); qn += __shfl_xor(qn, 2);
      if (l == 0)
        out[(size_t)(q0 + qq) * CC + cls] = num / fmaxf(sqrtf(qn) * sqrtf(pn), 1e-8f);
    }
  }
}

extern "C" void kernel_launch(void* const* d_in, const int* in_sizes, int n_in,
                              void* d_out, int out_size, void* d_ws, size_t ws_size,
                              hipStream_t stream) {
  const float* Sf     = (const float*)d_in[0];
  const int*   labels = (const int*)d_in[1];
  const float* qf     = (const float*)d_in[2];
  const float* W1     = (const float*)d_in[3];
  const float* b1     = (const float*)d_in[4];
  const float* W2     = (const float*)d_in[5];
  const float* b2     = (const float*)d_in[6];
  int S = in_sizes[1];
  int Q = in_sizes[2] / DD;

  float* ws    = (float*)d_ws;
  float* SumF  = ws + OFF_SUMF;
  float* B1c   = ws + OFF_B1C;
  float* h10   = ws + OFF_H10;
  float* pre   = ws + OFF_PRE;
  float* stats = ws + OFF_ST;
  float* out   = (float*)d_out;

  k_prep1<<<dim3(CC + 1), dim3(256), 0, stream>>>(Sf, labels, S, SumF, stats);
  k_prep2<<<dim3(CP + 1), dim3(256), 0, stream>>>(SumF, W1, b1, W2, b2, stats, B1c, h10, pre);
  int nb = (Q + 1) / 2;
  k_query<<<dim3(nb), dim3(256), 0, stream>>>(qf, W1, W2, b2, B1c, pre, stats, out, Q);
}

// Round 4
// 63.337 us; speedup vs baseline: 3.0491x; 3.0491x over previous
//
#include <hip/hip_runtime.h>

#define DD 512   // feature dim
#define H1 256   // hidden 1
#define H2 128   // hidden 2
#define CC 20    // real classes
#define CP 24    // padded classes
#define QPB 4    // queries per block in k_fused
#define MROWS (QPB*CP)   // 96 h1 rows per block
#define PSTR 132         // Pmat row stride (floats) - breaks bank alignment

typedef short v8s __attribute__((ext_vector_type(8)));
typedef float v4f __attribute__((ext_vector_type(4)));

// ---- static ws float offsets ----
#define OFF_SUMF 0
#define OFF_B1C  10240                  // CP*H1 rows
#define OFF_H10  16384
#define OFF_PRE  16640                  // CC*H2
#define OFF_ST   19200
#define NSTAT    97
#define OFF_U    19328                  // Q*H1 floats, then bf16 areas (dynamic)

static __device__ __forceinline__ unsigned short f2b(float f) {
  union { float f; unsigned int u; } v; v.f = f;
  unsigned int r = v.u + 0x7FFFu + ((v.u >> 16) & 1u);
  return (unsigned short)(r >> 16);
}

// ================= k_conv: prep1 + bf16/frag conversions =================
// blocks [0,CC): SumF ; block CC: stats ; then nqf qf-convert blocks;
// then 64 W1frag blocks ; then 16 W2frag blocks (skipped if nqf<0 style).
__global__ __launch_bounds__(256) void k_conv(
    const float* __restrict__ Sf, const int* __restrict__ labels, int S,
    float* __restrict__ SumF, float* __restrict__ stats,
    const float* __restrict__ qf, const float* __restrict__ W1,
    const float* __restrict__ W2,
    unsigned short* __restrict__ qb, unsigned short* __restrict__ w1f,
    unsigned short* __restrict__ w2f, int totqf, int nqf) {
  int b = blockIdx.x, t = threadIdx.x;
  if (b < CC) {
    __shared__ int lab[128];
    if (t < S && t < 128) lab[t] = labels[t];
    __syncthreads();
    for (int d = t; d < DD; d += 256) {
      float acc = 0.f;
      for (int j = 0; j < S; ++j)
        if (lab[j] == b) acc += Sf[j * DD + d];
      SumF[b * DD + d] = acc;
    }
  } else if (b == CC) {
    if (t < CP) {
      int cnt = 0;
      for (int j = 0; j < S; ++j) if (labels[j] == t) cnt++;
      float deg  = 1.f + (float)cnt;
      float dis  = rsqrtf(deg + 1e-6f);
      float dis0 = rsqrtf((float)S + 1e-6f);
      stats[1 + t]          = dis;
      stats[1 + CP + t]     = dis0 * dis;               // alpha
      stats[1 + 2*CP + t]   = dis * dis * (float)cnt;   // beta (0 pad)
      stats[1 + 3*CP + t]   = dis * (float)cnt;         // gamma (0 pad)
      if (t == 0) stats[0] = dis0;
    }
  } else if (b < CC + 1 + nqf) {
    int idx = (b - CC - 1) * 2048 + t * 8;
    if (idx + 7 < totqf) {
      float4 a = *(const float4*)&qf[idx];
      float4 c = *(const float4*)&qf[idx + 4];
      __align__(16) unsigned short o[8];
      o[0]=f2b(a.x); o[1]=f2b(a.y); o[2]=f2b(a.z); o[3]=f2b(a.w);
      o[4]=f2b(c.x); o[5]=f2b(c.y); o[6]=f2b(c.z); o[7]=f2b(c.w);
      *(v8s*)&qb[idx] = *(const v8s*)o;
    } else {
      for (int e = 0; e < 8; ++e) if (idx + e < totqf) qb[idx + e] = f2b(qf[idx + e]);
    }
  } else if (b < CC + 1 + nqf + 64) {
    // W1frag: frag = nt*16+ks (nt<16, ks<16); lane elem e: W1[ks*32+lg*8+e][nt*16+lr]
    int frag = (b - CC - 1 - nqf) * 4 + (t >> 6);
    int l = t & 63, lr = l & 15, lg = l >> 4;
    int nt = frag >> 4, ks = frag & 15;
    __align__(16) unsigned short o[8];
#pragma unroll
    for (int e = 0; e < 8; ++e)
      o[e] = f2b(W1[(ks * 32 + lg * 8 + e) * H1 + nt * 16 + lr]);
    *(v8s*)&w1f[frag * 512 + l * 8] = *(const v8s*)o;
  } else {
    // W2frag: frag = nt*8+ks (nt<8, ks<8)
    int frag = (b - CC - 1 - nqf - 64) * 4 + (t >> 6);
    int l = t & 63, lr = l & 15, lg = l >> 4;
    int nt = frag >> 3, ks = frag & 7;
    __align__(16) unsigned short o[8];
#pragma unroll
    for (int e = 0; e < 8; ++e)
      o[e] = f2b(W2[(ks * 32 + lg * 8 + e) * H2 + nt * 16 + lr]);
    *(v8s*)&w2f[frag * 512 + l * 8] = *(const v8s*)o;
  }
}

// ================= prep2: B1c rows, h1_0, pre_ck (f32, unchanged) =================
__global__ __launch_bounds__(256) void k_prep2(
    const float* __restrict__ SumF, const float* __restrict__ W1,
    const float* __restrict__ b1, const float* __restrict__ W2,
    const float* __restrict__ b2, const float* __restrict__ stats,
    float* __restrict__ B1c, float* __restrict__ h10, float* __restrict__ pre) {
  int b = blockIdx.x, tid = threadIdx.x;
  if (b < CC) {
    float dis = stats[1 + b];
    float sc = dis * dis;
    float acc = 0.f;
#pragma unroll 4
    for (int d = 0; d < DD; ++d) acc += SumF[b * DD + d] * W1[d * H1 + tid];
    B1c[b * H1 + tid] = b1[tid] + sc * acc;
  } else if (b < CP) {
    B1c[b * H1 + tid] = 0.f;
  } else {
    __shared__ float row0[DD];
    __shared__ float h10l[H1];
    float dis0 = stats[0];
    for (int d = tid; d < DD; d += 256) {
      float acc = 0.f;
#pragma unroll
      for (int c = 0; c < CC; ++c) acc += stats[1 + c] * SumF[c * DD + d];
      row0[d] = dis0 * acc;
    }
    __syncthreads();
    float acc = 0.f;
#pragma unroll 4
    for (int d = 0; d < DD; ++d) acc += row0[d] * W1[d * H1 + tid];
    float h = fmaxf(b1[tid] + acc, 0.f);
    h10l[tid] = h;
    h10[tid] = h;
    __syncthreads();
    if (tid < H2) {
      float g = 0.f;
#pragma unroll 4
      for (int j = 0; j < H1; ++j) g += h10l[j] * W2[j * H2 + tid];
      float bb = b2[tid];
#pragma unroll
      for (int c = 0; c < CC; ++c)
        pre[c * H2 + tid] = dis0 * stats[1 + c] * g + bb;
    }
  }
}

// ================= k_gemmu: U = qf_bf16 @ W1_bf16 (MFMA) =================
__global__ __launch_bounds__(256) void k_gemmu(
    const unsigned short* __restrict__ qb, const unsigned short* __restrict__ w1f,
    float* __restrict__ U, int Q) {
  int bm = blockIdx.x >> 2, bn = blockIdx.x & 3;
  int t = threadIdx.x, w = t >> 6, l = t & 63;
  int mh = w >> 1, nh = w & 1;
  int m0 = bm * 64 + mh * 32, n0 = bn * 64 + nh * 32;
  int lr = l & 15, lg = l >> 4;
  v4f acc[2][2];
#pragma unroll
  for (int i = 0; i < 2; ++i)
#pragma unroll
    for (int j = 0; j < 2; ++j) acc[i][j] = (v4f){0.f, 0.f, 0.f, 0.f};
  int r0 = m0 + lr;      if (r0 >= Q) r0 = Q - 1;
  int r1 = m0 + 16 + lr; if (r1 >= Q) r1 = Q - 1;
  int ntg = bn * 4 + nh * 2;
#pragma unroll 2
  for (int ks = 0; ks < 16; ++ks) {
    const v8s a0 = *(const v8s*)(qb + (size_t)r0 * DD + ks * 32 + lg * 8);
    const v8s a1 = *(const v8s*)(qb + (size_t)r1 * DD + ks * 32 + lg * 8);
    const v8s b0 = *(const v8s*)(w1f + ((ntg * 16 + ks) * 512 + l * 8));
    const v8s b1 = *(const v8s*)(w1f + (((ntg + 1) * 16 + ks) * 512 + l * 8));
    acc[0][0] = __builtin_amdgcn_mfma_f32_16x16x32_bf16(a0, b0, acc[0][0], 0, 0, 0);
    acc[0][1] = __builtin_amdgcn_mfma_f32_16x16x32_bf16(a0, b1, acc[0][1], 0, 0, 0);
    acc[1][0] = __builtin_amdgcn_mfma_f32_16x16x32_bf16(a1, b0, acc[1][0], 0, 0, 0);
    acc[1][1] = __builtin_amdgcn_mfma_f32_16x16x32_bf16(a1, b1, acc[1][1], 0, 0, 0);
  }
#pragma unroll
  for (int mt = 0; mt < 2; ++mt)
#pragma unroll
    for (int nt = 0; nt < 2; ++nt)
#pragma unroll
      for (int r = 0; r < 4; ++r) {
        int row = m0 + mt * 16 + lg * 4 + r;
        if (row < Q)
          U[(size_t)row * H1 + n0 + nt * 16 + lr] = acc[mt][nt][r];
      }
}

// ================= k_fused: 4 queries/block, MFMA P-GEMM + epilogue =================
__global__ __launch_bounds__(256) void k_fused(
    const float* __restrict__ U, const float* __restrict__ B1c,
    const float* __restrict__ pre, const float* __restrict__ stats,
    const float* __restrict__ b2, const unsigned short* __restrict__ w2f,
    float* __restrict__ out, int Q) {
  __shared__ float smem[MROWS * PSTR];   // 50688 B: h1(bf16) then Pmat(f32), aliased
  __shared__ float us[QPB * H1];
  __shared__ float qe[QPB * H2];
  __shared__ float qn[QPB];
  __shared__ float stc[NSTAT];
  unsigned short* hb = (unsigned short*)smem;
  float* Pm = smem;

  int t = threadIdx.x, q0 = blockIdx.x * QPB;
  if (t < NSTAT) stc[t] = stats[t];
  // stage U rows (coalesced)
#pragma unroll
  for (int i = 0; i < 4; ++i) {
    int idx = t + 256 * i, r = idx >> 8;
    us[idx] = (q0 + r < Q) ? U[(size_t)(q0 + r) * H1 + (idx & 255)] : 0.f;
  }
  __syncthreads();

  // build h1 (bf16, XOR-swizzled 16B chunks)
#pragma unroll 4
  for (int i = 0; i < 12; ++i) {
    int ch = t + 256 * i;
    int r = ch >> 5, jc = ch & 31;
    int q = r / 24, c = r - q * 24;
    float al = stc[1 + CP + c];
    const float4 u0 = *(const float4*)&us[q * H1 + jc * 8];
    const float4 u1 = *(const float4*)&us[q * H1 + jc * 8 + 4];
    const float4 g0 = *(const float4*)&B1c[c * H1 + jc * 8];
    const float4 g1 = *(const float4*)&B1c[c * H1 + jc * 8 + 4];
    __align__(16) unsigned short o[8];
    o[0] = f2b(fmaxf(fmaf(al, u0.x, g0.x), 0.f));
    o[1] = f2b(fmaxf(fmaf(al, u0.y, g0.y), 0.f));
    o[2] = f2b(fmaxf(fmaf(al, u0.z, g0.z), 0.f));
    o[3] = f2b(fmaxf(fmaf(al, u0.w, g0.w), 0.f));
    o[4] = f2b(fmaxf(fmaf(al, u1.x, g1.x), 0.f));
    o[5] = f2b(fmaxf(fmaf(al, u1.y, g1.y), 0.f));
    o[6] = f2b(fmaxf(fmaf(al, u1.z, g1.z), 0.f));
    o[7] = f2b(fmaxf(fmaf(al, u1.w, g1.w), 0.f));
    int uidx = (r * 256 + jc * 8) ^ ((r & 7) << 3);
    *(v8s*)&hb[uidx] = *(const v8s*)o;
  }
  __syncthreads();

  // MFMA: wave w owns N-tiles {2w, 2w+1}; 6 M-tiles x 8 k-steps
  int w = t >> 6, l = t & 63, lr = l & 15, lg = l >> 4;
  v4f acc[6][2];
#pragma unroll
  for (int mt = 0; mt < 6; ++mt) {
    acc[mt][0] = (v4f){0.f, 0.f, 0.f, 0.f};
    acc[mt][1] = (v4f){0.f, 0.f, 0.f, 0.f};
  }
#pragma unroll
  for (int ks = 0; ks < 8; ++ks) {
    const v8s b0 = *(const v8s*)(w2f + (((w * 2 + 0) * 8 + ks) * 512 + l * 8));
    const v8s b1 = *(const v8s*)(w2f + (((w * 2 + 1) * 8 + ks) * 512 + l * 8));
#pragma unroll
    for (int mt = 0; mt < 6; ++mt) {
      int row = mt * 16 + lr;
      const v8s a = *(const v8s*)&hb[(row * 256 + ks * 32 + lg * 8) ^ ((row & 7) << 3)];
      acc[mt][0] = __builtin_amdgcn_mfma_f32_16x16x32_bf16(a, b0, acc[mt][0], 0, 0, 0);
      acc[mt][1] = __builtin_amdgcn_mfma_f32_16x16x32_bf16(a, b1, acc[mt][1], 0, 0, 0);
    }
  }
  __syncthreads();   // all h1 reads complete before aliasing as Pmat

  // scatter D fragments -> Pm[row][col]
#pragma unroll
  for (int mt = 0; mt < 6; ++mt)
#pragma unroll
    for (int nt = 0; nt < 2; ++nt)
#pragma unroll
      for (int r = 0; r < 4; ++r)
        Pm[(mt * 16 + lg * 4 + r) * PSTR + (w * 2 + nt) * 16 + lr] = acc[mt][nt][r];
  __syncthreads();

  // qe[q][k] = relu(dis0 * sum_c gamma_c P[q,c,k] + b2[k])
#pragma unroll
  for (int rep = 0; rep < 2; ++rep) {
    int q = (t >> 7) + rep * 2, k = t & 127;
    float s = 0.f;
#pragma unroll
    for (int c = 0; c < CC; ++c) s = fmaf(stc[1 + 3 * CP + c], Pm[(q * 24 + c) * PSTR + k], s);
    qe[q * H2 + k] = fmaxf(fmaf(stc[0], s, b2[k]), 0.f);
  }
  __syncthreads();

  // qn[q] = |qe_q|^2
  if (t < 128) {
    int q = t >> 5, ln = t & 31;
    float s = 0.f;
#pragma unroll
    for (int i = 0; i < 4; ++i) { float e = qe[q * H2 + ln + 32 * i]; s = fmaf(e, e, s); }
    s += __shfl_xor(s, 1); s += __shfl_xor(s, 2); s += __shfl_xor(s, 4);
    s += __shfl_xor(s, 8); s += __shfl_xor(s, 16);
    if (ln == 0) qn[q] = s;
  }
  __syncthreads();

  // cosine: 4-lane groups per (q, c)
#pragma unroll
  for (int rep = 0; rep < 2; ++rep) {
    int q = (t >> 7) + rep * 2;
    int sub = t & 127, c = sub >> 2, lcl = sub & 3;
    if (c < CC && q0 + q < Q) {
      float num = 0.f, pn = 0.f;
      int rowb = (q * 24 + c) * PSTR;
      float bet = stc[1 + 2 * CP + c];
#pragma unroll
      for (int i = 0; i < 32; ++i) {
        int k = lcl + 4 * i;
        float P = Pm[rowb + k];
        float pr = fmaxf(pre[c * H2 + k] + bet * P, 0.f);
        float e = qe[q * H2 + k];
        num = fmaf(e, pr, num); pn = fmaf(pr, pr, pn);
      }
      num += __shfl_xor(num, 1); pn += __shfl_xor(pn, 1);
      num += __shfl_xor(num, 2); pn += __shfl_xor(pn, 2);
      if (lcl == 0)
        out[(size_t)(q0 + q) * CC + c] = num / fmaxf(sqrtf(qn[q]) * sqrtf(pn), 1e-8f);
    }
  }
}

// ================= fallback (ws too small): r2's proven VALU kernel =================
__global__ __launch_bounds__(256) void k_fb(
    const float* __restrict__ qf, const float* __restrict__ W1,
    const float* __restrict__ W2, const float* __restrict__ b2,
    const float* __restrict__ B1c, const float* __restrict__ pre_ck,
    const float* __restrict__ stats, float* __restrict__ out, int Q) {
  __shared__ __align__(16) float h1[CP][H1];
  __shared__ __align__(16) float proto[CC][H2 + 4];
  __shared__ __align__(16) float psum[8][H2];
  __shared__ float qel[H2];
  __shared__ float stc[NSTAT];
  int tid = threadIdx.x, q = blockIdx.x;
  if (tid < NSTAT) stc[tid] = stats[tid];
  float uvacc = 0.f;
  for (int d = 0; d < DD; ++d) uvacc += qf[(size_t)q * DD + d] * W1[d * H1 + tid];
  __syncthreads();
#pragma unroll
  for (int r = 0; r < CP; ++r)
    h1[r][tid] = fmaxf(stc[1 + CP + r] * uvacc + B1c[r * H1 + tid], 0.f);
  __syncthreads();
  int sg = tid >> 5, kq = tid & 31, k4 = kq * 4, cb = sg * 3;
  float a[3][4];
#pragma unroll
  for (int i = 0; i < 3; ++i)
#pragma unroll
    for (int kk = 0; kk < 4; ++kk) a[i][kk] = 0.f;
  const float4* W2v = (const float4*)W2;
#pragma unroll 2
  for (int j0 = 0; j0 < H1; j0 += 4) {
    float wv[4][4]; float4 hh[3];
#pragma unroll
    for (int jj = 0; jj < 4; ++jj) {
      float4 tv = W2v[(j0 + jj) * 32 + kq];
      wv[jj][0] = tv.x; wv[jj][1] = tv.y; wv[jj][2] = tv.z; wv[jj][3] = tv.w;
    }
#pragma unroll
    for (int i = 0; i < 3; ++i) hh[i] = *(const float4*)&h1[cb + i][j0];
#pragma unroll
    for (int i = 0; i < 3; ++i)
#pragma unroll
      for (int jj = 0; jj < 4; ++jj) {
        float h = ((const float*)&hh[i])[jj];
#pragma unroll
        for (int kk = 0; kk < 4; ++kk) a[i][kk] = fmaf(h, wv[jj][kk], a[i][kk]);
      }
  }
  {
    __align__(16) float part[4] = {0.f, 0.f, 0.f, 0.f};
#pragma unroll
    for (int i = 0; i < 3; ++i) {
      int c = cb + i;
      float gam = stc[1 + 3 * CP + c];
#pragma unroll
      for (int kk = 0; kk < 4; ++kk) part[kk] += gam * a[i][kk];
      if (c < CC) {
        float bet = stc[1 + 2 * CP + c];
        float4 pv = *(const float4*)&pre_ck[c * H2 + k4];
        float4 pr;
        pr.x = fmaxf(pv.x + bet * a[i][0], 0.f);
        pr.y = fmaxf(pv.y + bet * a[i][1], 0.f);
        pr.z = fmaxf(pv.z + bet * a[i][2], 0.f);
        pr.w = fmaxf(pv.w + bet * a[i][3], 0.f);
        *(float4*)&proto[c][k4] = pr;
      }
    }
    *(float4*)&psum[sg][k4] = *(const float4*)part;
  }
  __syncthreads();
  if (tid < H2) {
    float s = 0.f;
#pragma unroll
    for (int g = 0; g < 8; ++g) s += psum[g][tid];
    qel[tid] = fmaxf(stc[0] * s + b2[tid], 0.f);
  }
  __syncthreads();
  if (tid < 160) {
    int c = tid >> 3, ln = tid & 7;
    float num = 0.f, pn = 0.f, qnn = 0.f;
#pragma unroll
    for (int i = 0; i < 16; ++i) {
      int k = ln + 8 * i;
      float e = qel[k], p = proto[c][k];
      num = fmaf(e, p, num); pn = fmaf(p, p, pn); qnn = fmaf(e, e, qnn);
    }
    num += __shfl_xor(num, 1); pn += __shfl_xor(pn, 1); qnn += __shfl_xor(qnn, 1);
    num += __shfl_xor(num, 2); pn += __shfl_xor(pn, 2); qnn += __shfl_xor(qnn, 2);
    num += __shfl_xor(num, 4); pn += __shfl_xor(pn, 4); qnn += __shfl_xor(qnn, 4);
    if (ln == 0)
      out[(size_t)q * CC + c] = num / fmaxf(sqrtf(qnn) * sqrtf(pn), 1e-8f);
  }
}

extern "C" void kernel_launch(void* const* d_in, const int* in_sizes, int n_in,
                              void* d_out, int out_size, void* d_ws, size_t ws_size,
                              hipStream_t stream) {
  const float* Sf     = (const float*)d_in[0];
  const int*   labels = (const int*)d_in[1];
  const float* qf     = (const float*)d_in[2];
  const float* W1     = (const float*)d_in[3];
  const float* b1     = (const float*)d_in[4];
  const float* W2     = (const float*)d_in[5];
  const float* b2     = (const float*)d_in[6];
  int S = in_sizes[1];
  int Q = in_sizes[2] / DD;

  float* ws    = (float*)d_ws;
  float* SumF  = ws + OFF_SUMF;
  float* B1c   = ws + OFF_B1C;
  float* h10   = ws + OFF_H10;
  float* pre   = ws + OFF_PRE;
  float* stats = ws + OFF_ST;
  float* Uptr  = ws + OFF_U;
  float* out   = (float*)d_out;

  int totqf = Q * DD;
  int nqf = (totqf + 2047) / 2048;
  // dynamic bf16 areas (float-slot offsets)
  size_t off_qb  = OFF_U + (size_t)Q * H1;
  size_t off_w1f = off_qb + (size_t)totqf / 2;
  size_t off_w2f = off_w1f + 65536;
  size_t req     = (off_w2f + 16384) * sizeof(float);
  unsigned short* qb  = (unsigned short*)(ws + off_qb);
  unsigned short* w1f = (unsigned short*)(ws + off_w1f);
  unsigned short* w2f = (unsigned short*)(ws + off_w2f);

  bool fast = ws_size >= req;

  if (fast) {
    k_conv<<<dim3(CC + 1 + nqf + 64 + 16), dim3(256), 0, stream>>>(
        Sf, labels, S, SumF, stats, qf, W1, W2, qb, w1f, w2f, totqf, nqf);
    k_prep2<<<dim3(CP + 1), dim3(256), 0, stream>>>(SumF, W1, b1, W2, b2, stats, B1c, h10, pre);
    int mb = (Q + 63) / 64;
    k_gemmu<<<dim3(mb * 4), dim3(256), 0, stream>>>(qb, w1f, Uptr, Q);
    k_fused<<<dim3((Q + QPB - 1) / QPB), dim3(256), 0, stream>>>(
        Uptr, B1c, pre, stats, b2, w2f, out, Q);
  } else {
    k_conv<<<dim3(CC + 1), dim3(256), 0, stream>>>(
        Sf, labels, S, SumF, stats, qf, W1, W2, qb, w1f, w2f, 0, 0);
    k_prep2<<<dim3(CP + 1), dim3(256), 0, stream>>>(SumF, W1, b1, W2, b2, stats, B1c, h10, pre);
    k_fb<<<dim3(Q), dim3(256), 0, stream>>>(qf, W1, W2, b2, B1c, pre, stats, out, Q);
  }
}

// Round 5
// 54.105 us; speedup vs baseline: 3.5694x; 1.1706x over previous
//
#include <hip/hip_runtime.h>

#define DD 512   // feature dim
#define H1 256   // hidden 1
#define H2 128   // hidden 2
#define CC 20    // real classes
#define CP 24    // padded classes
#define QPB 4    // queries per block in k_fused
#define MROWS (QPB*CP)   // 96 h1 rows per block
#define PSTR 132         // Pmat row stride (floats)
#define NDC 4            // d-chunks for split-K prep
#define DCH (DD/NDC)     // 128

typedef short v8s __attribute__((ext_vector_type(8)));
typedef float v4f __attribute__((ext_vector_type(4)));

// ---- static ws float offsets ----
#define OFF_SUMF 0
#define OFF_B1C  10240
#define OFF_H10  16384
#define OFF_PRE  16640
#define OFF_ST   19200
#define NSTAT    97
#define OFF_U    19328   // Q*H1 floats (fast path); also scratch for prep partials

static __device__ __forceinline__ unsigned short f2b(float f) {
  union { float f; unsigned int u; } v; v.f = f;
  unsigned int r = v.u + 0x7FFFu + ((v.u >> 16) & 1u);
  return (unsigned short)(r >> 16);
}

// ================= k_conv: prep1 + bf16/frag conversions =================
__global__ __launch_bounds__(256) void k_conv(
    const float* __restrict__ Sf, const int* __restrict__ labels, int S,
    float* __restrict__ SumF, float* __restrict__ stats,
    const float* __restrict__ qf, const float* __restrict__ W1,
    const float* __restrict__ W2,
    unsigned short* __restrict__ qb, unsigned short* __restrict__ w1f,
    unsigned short* __restrict__ w2f, int totqf, int nqf) {
  int b = blockIdx.x, t = threadIdx.x;
  if (b < CC) {
    __shared__ int lab[128];
    if (t < S && t < 128) lab[t] = labels[t];
    __syncthreads();
    for (int d = t; d < DD; d += 256) {
      float acc = 0.f;
      for (int j = 0; j < S; ++j)
        if (lab[j] == b) acc += Sf[j * DD + d];
      SumF[b * DD + d] = acc;
    }
  } else if (b == CC) {
    if (t < CP) {
      int cnt = 0;
      for (int j = 0; j < S; ++j) if (labels[j] == t) cnt++;
      float deg  = 1.f + (float)cnt;
      float dis  = rsqrtf(deg + 1e-6f);
      float dis0 = rsqrtf((float)S + 1e-6f);
      stats[1 + t]          = dis;
      stats[1 + CP + t]     = dis0 * dis;               // alpha
      stats[1 + 2*CP + t]   = dis * dis * (float)cnt;   // beta (0 pad)
      stats[1 + 3*CP + t]   = dis * (float)cnt;         // gamma (0 pad)
      if (t == 0) stats[0] = dis0;
    }
  } else if (b < CC + 1 + nqf) {
    int idx = (b - CC - 1) * 2048 + t * 8;
    if (idx + 7 < totqf) {
      float4 a = *(const float4*)&qf[idx];
      float4 c = *(const float4*)&qf[idx + 4];
      __align__(16) unsigned short o[8];
      o[0]=f2b(a.x); o[1]=f2b(a.y); o[2]=f2b(a.z); o[3]=f2b(a.w);
      o[4]=f2b(c.x); o[5]=f2b(c.y); o[6]=f2b(c.z); o[7]=f2b(c.w);
      *(v8s*)&qb[idx] = *(const v8s*)o;
    } else {
      for (int e = 0; e < 8; ++e) if (idx + e < totqf) qb[idx + e] = f2b(qf[idx + e]);
    }
  } else if (b < CC + 1 + nqf + 64) {
    int frag = (b - CC - 1 - nqf) * 4 + (t >> 6);
    int l = t & 63, lr = l & 15, lg = l >> 4;
    int nt = frag >> 4, ks = frag & 15;
    __align__(16) unsigned short o[8];
#pragma unroll
    for (int e = 0; e < 8; ++e)
      o[e] = f2b(W1[(ks * 32 + lg * 8 + e) * H1 + nt * 16 + lr]);
    *(v8s*)&w1f[frag * 512 + l * 8] = *(const v8s*)o;
  } else {
    int frag = (b - CC - 1 - nqf - 64) * 4 + (t >> 6);
    int l = t & 63, lr = l & 15, lg = l >> 4;
    int nt = frag >> 3, ks = frag & 7;
    __align__(16) unsigned short o[8];
#pragma unroll
    for (int e = 0; e < 8; ++e)
      o[e] = f2b(W2[(ks * 32 + lg * 8 + e) * H2 + nt * 16 + lr]);
    *(v8s*)&w2f[frag * 512 + l * 8] = *(const v8s*)o;
  }
}

// ================= k_p2a: partial[c][dc][n] = Sum_{d in chunk} SumF[c][d]*W1[d][n] =====
__global__ __launch_bounds__(256) void k_p2a(
    const float* __restrict__ SumF, const float* __restrict__ W1,
    float* __restrict__ part) {
  int c = blockIdx.x >> 2, dc = blockIdx.x & 3;
  int n = threadIdx.x;
  int d0 = dc * DCH;
  const float* __restrict__ A  = SumF + c * DD + d0;   // wave-uniform -> s_load
  const float* __restrict__ Wp = W1 + (size_t)d0 * H1 + n;
  float acc = 0.f;
#pragma unroll 8
  for (int d = 0; d < DCH; ++d)
    acc = fmaf(A[d], Wp[(size_t)d * H1], acc);
  part[(c * NDC + dc) * H1 + n] = acc;
}

// ================= k_p2r: finalize B1c rows, pad rows, h10 ==============
__global__ __launch_bounds__(256) void k_p2r(
    const float* __restrict__ part, const float* __restrict__ b1,
    const float* __restrict__ stats, float* __restrict__ B1c,
    float* __restrict__ h10) {
  int b = blockIdx.x, n = threadIdx.x;
  if (b < CC) {
    float dot = part[(b * NDC + 0) * H1 + n] + part[(b * NDC + 1) * H1 + n]
              + part[(b * NDC + 2) * H1 + n] + part[(b * NDC + 3) * H1 + n];
    float dis = stats[1 + b];
    B1c[b * H1 + n] = fmaf(dis * dis, dot, b1[n]);
  } else {
#pragma unroll
    for (int c = CC; c < CP; ++c) B1c[c * H1 + n] = 0.f;
    float s = 0.f;
#pragma unroll 4
    for (int c = 0; c < CC; ++c) {
      float dot = part[(c * NDC + 0) * H1 + n] + part[(c * NDC + 1) * H1 + n]
                + part[(c * NDC + 2) * H1 + n] + part[(c * NDC + 3) * H1 + n];
      s = fmaf(stats[1 + c], dot, s);
    }
    h10[n] = fmaxf(fmaf(stats[0], s, b1[n]), 0.f);
  }
}

// ================= k_pre2: pre_ck[c][k] = dis0*dis_c*(h10@W2)[k] + b2[k] ==========
__global__ __launch_bounds__(256) void k_pre2(
    const float* __restrict__ h10, const float* __restrict__ W2,
    const float* __restrict__ b2, const float* __restrict__ stats,
    float* __restrict__ pre) {
  __shared__ float red[256];
  int t = threadIdx.x, k = t & 127, jh = t >> 7;
  float g = 0.f;
#pragma unroll 8
  for (int j = jh * 128; j < jh * 128 + 128; ++j)
    g = fmaf(h10[j], W2[j * H2 + k], g);      // h10[j] wave-uniform -> s_load
  red[t] = g;
  __syncthreads();
  if (t < 128) {
    g = red[t] + red[t + 128];
    float d0 = stats[0], bb = b2[k];
#pragma unroll
    for (int c = 0; c < CC; ++c)
      pre[c * H2 + k] = fmaf(d0 * stats[1 + c], g, bb);
  }
}

// ================= k_gemmu: U = qf_bf16 @ W1_bf16 (MFMA) =================
__global__ __launch_bounds__(256) void k_gemmu(
    const unsigned short* __restrict__ qb, const unsigned short* __restrict__ w1f,
    float* __restrict__ U, int Q) {
  int bm = blockIdx.x >> 2, bn = blockIdx.x & 3;
  int t = threadIdx.x, w = t >> 6, l = t & 63;
  int mh = w >> 1, nh = w & 1;
  int m0 = bm * 64 + mh * 32, n0 = bn * 64 + nh * 32;
  int lr = l & 15, lg = l >> 4;
  v4f acc[2][2];
#pragma unroll
  for (int i = 0; i < 2; ++i)
#pragma unroll
    for (int j = 0; j < 2; ++j) acc[i][j] = (v4f){0.f, 0.f, 0.f, 0.f};
  int r0 = m0 + lr;      if (r0 >= Q) r0 = Q - 1;
  int r1 = m0 + 16 + lr; if (r1 >= Q) r1 = Q - 1;
  int ntg = bn * 4 + nh * 2;
#pragma unroll 2
  for (int ks = 0; ks < 16; ++ks) {
    const v8s a0 = *(const v8s*)(qb + (size_t)r0 * DD + ks * 32 + lg * 8);
    const v8s a1 = *(const v8s*)(qb + (size_t)r1 * DD + ks * 32 + lg * 8);
    const v8s b0 = *(const v8s*)(w1f + ((ntg * 16 + ks) * 512 + l * 8));
    const v8s b1 = *(const v8s*)(w1f + (((ntg + 1) * 16 + ks) * 512 + l * 8));
    acc[0][0] = __builtin_amdgcn_mfma_f32_16x16x32_bf16(a0, b0, acc[0][0], 0, 0, 0);
    acc[0][1] = __builtin_amdgcn_mfma_f32_16x16x32_bf16(a0, b1, acc[0][1], 0, 0, 0);
    acc[1][0] = __builtin_amdgcn_mfma_f32_16x16x32_bf16(a1, b0, acc[1][0], 0, 0, 0);
    acc[1][1] = __builtin_amdgcn_mfma_f32_16x16x32_bf16(a1, b1, acc[1][1], 0, 0, 0);
  }
#pragma unroll
  for (int mt = 0; mt < 2; ++mt)
#pragma unroll
    for (int nt = 0; nt < 2; ++nt)
#pragma unroll
      for (int r = 0; r < 4; ++r) {
        int row = m0 + mt * 16 + lg * 4 + r;
        if (row < Q)
          U[(size_t)row * H1 + n0 + nt * 16 + lr] = acc[mt][nt][r];
      }
}

// ================= k_fused: 4 queries/block, MFMA P-GEMM + epilogue =================
__global__ __launch_bounds__(256) void k_fused(
    const float* __restrict__ U, const float* __restrict__ B1c,
    const float* __restrict__ pre, const float* __restrict__ stats,
    const float* __restrict__ b2, const unsigned short* __restrict__ w2f,
    float* __restrict__ out, int Q) {
  __shared__ float smem[MROWS * PSTR];
  __shared__ float us[QPB * H1];
  __shared__ float qe[QPB * H2];
  __shared__ float qn[QPB];
  __shared__ float stc[NSTAT];
  unsigned short* hb = (unsigned short*)smem;
  float* Pm = smem;

  int t = threadIdx.x, q0 = blockIdx.x * QPB;
  if (t < NSTAT) stc[t] = stats[t];
#pragma unroll
  for (int i = 0; i < 4; ++i) {
    int idx = t + 256 * i, r = idx >> 8;
    us[idx] = (q0 + r < Q) ? U[(size_t)(q0 + r) * H1 + (idx & 255)] : 0.f;
  }
  __syncthreads();

#pragma unroll 4
  for (int i = 0; i < 12; ++i) {
    int ch = t + 256 * i;
    int r = ch >> 5, jc = ch & 31;
    int q = r / 24, c = r - q * 24;
    float al = stc[1 + CP + c];
    const float4 u0 = *(const float4*)&us[q * H1 + jc * 8];
    const float4 u1 = *(const float4*)&us[q * H1 + jc * 8 + 4];
    const float4 g0 = *(const float4*)&B1c[c * H1 + jc * 8];
    const float4 g1 = *(const float4*)&B1c[c * H1 + jc * 8 + 4];
    __align__(16) unsigned short o[8];
    o[0] = f2b(fmaxf(fmaf(al, u0.x, g0.x), 0.f));
    o[1] = f2b(fmaxf(fmaf(al, u0.y, g0.y), 0.f));
    o[2] = f2b(fmaxf(fmaf(al, u0.z, g0.z), 0.f));
    o[3] = f2b(fmaxf(fmaf(al, u0.w, g0.w), 0.f));
    o[4] = f2b(fmaxf(fmaf(al, u1.x, g1.x), 0.f));
    o[5] = f2b(fmaxf(fmaf(al, u1.y, g1.y), 0.f));
    o[6] = f2b(fmaxf(fmaf(al, u1.z, g1.z), 0.f));
    o[7] = f2b(fmaxf(fmaf(al, u1.w, g1.w), 0.f));
    int uidx = (r * 256 + jc * 8) ^ ((r & 7) << 3);
    *(v8s*)&hb[uidx] = *(const v8s*)o;
  }
  __syncthreads();

  int w = t >> 6, l = t & 63, lr = l & 15, lg = l >> 4;
  v4f acc[6][2];
#pragma unroll
  for (int mt = 0; mt < 6; ++mt) {
    acc[mt][0] = (v4f){0.f, 0.f, 0.f, 0.f};
    acc[mt][1] = (v4f){0.f, 0.f, 0.f, 0.f};
  }
#pragma unroll
  for (int ks = 0; ks < 8; ++ks) {
    const v8s b0 = *(const v8s*)(w2f + (((w * 2 + 0) * 8 + ks) * 512 + l * 8));
    const v8s b1 = *(const v8s*)(w2f + (((w * 2 + 1) * 8 + ks) * 512 + l * 8));
#pragma unroll
    for (int mt = 0; mt < 6; ++mt) {
      int row = mt * 16 + lr;
      const v8s a = *(const v8s*)&hb[(row * 256 + ks * 32 + lg * 8) ^ ((row & 7) << 3)];
      acc[mt][0] = __builtin_amdgcn_mfma_f32_16x16x32_bf16(a, b0, acc[mt][0], 0, 0, 0);
      acc[mt][1] = __builtin_amdgcn_mfma_f32_16x16x32_bf16(a, b1, acc[mt][1], 0, 0, 0);
    }
  }
  __syncthreads();

#pragma unroll
  for (int mt = 0; mt < 6; ++mt)
#pragma unroll
    for (int nt = 0; nt < 2; ++nt)
#pragma unroll
      for (int r = 0; r < 4; ++r)
        Pm[(mt * 16 + lg * 4 + r) * PSTR + (w * 2 + nt) * 16 + lr] = acc[mt][nt][r];
  __syncthreads();

#pragma unroll
  for (int rep = 0; rep < 2; ++rep) {
    int q = (t >> 7) + rep * 2, k = t & 127;
    float s = 0.f;
#pragma unroll
    for (int c = 0; c < CC; ++c) s = fmaf(stc[1 + 3 * CP + c], Pm[(q * 24 + c) * PSTR + k], s);
    qe[q * H2 + k] = fmaxf(fmaf(stc[0], s, b2[k]), 0.f);
  }
  __syncthreads();

  if (t < 128) {
    int q = t >> 5, ln = t & 31;
    float s = 0.f;
#pragma unroll
    for (int i = 0; i < 4; ++i) { float e = qe[q * H2 + ln + 32 * i]; s = fmaf(e, e, s); }
    s += __shfl_xor(s, 1); s += __shfl_xor(s, 2); s += __shfl_xor(s, 4);
    s += __shfl_xor(s, 8); s += __shfl_xor(s, 16);
    if (ln == 0) qn[q] = s;
  }
  __syncthreads();

#pragma unroll
  for (int rep = 0; rep < 2; ++rep) {
    int q = (t >> 7) + rep * 2;
    int sub = t & 127, c = sub >> 2, lcl = sub & 3;
    if (c < CC && q0 + q < Q) {
      float num = 0.f, pn = 0.f;
      int rowb = (q * 24 + c) * PSTR;
      float bet = stc[1 + 2 * CP + c];
#pragma unroll
      for (int i = 0; i < 32; ++i) {
        int k = lcl + 4 * i;
        float P = Pm[rowb + k];
        float pr = fmaxf(pre[c * H2 + k] + bet * P, 0.f);
        float e = qe[q * H2 + k];
        num = fmaf(e, pr, num); pn = fmaf(pr, pr, pn);
      }
      num += __shfl_xor(num, 1); pn += __shfl_xor(pn, 1);
      num += __shfl_xor(num, 2); pn += __shfl_xor(pn, 2);
      if (lcl == 0)
        out[(size_t)(q0 + q) * CC + c] = num / fmaxf(sqrtf(qn[q]) * sqrtf(pn), 1e-8f);
    }
  }
}

// ================= fallback (ws too small): proven VALU kernel =================
__global__ __launch_bounds__(256) void k_fb(
    const float* __restrict__ qf, const float* __restrict__ W1,
    const float* __restrict__ W2, const float* __restrict__ b2,
    const float* __restrict__ B1c, const float* __restrict__ pre_ck,
    const float* __restrict__ stats, float* __restrict__ out, int Q) {
  __shared__ __align__(16) float h1[CP][H1];
  __shared__ __align__(16) float proto[CC][H2 + 4];
  __shared__ __align__(16) float psum[8][H2];
  __shared__ float qel[H2];
  __shared__ float stc[NSTAT];
  int tid = threadIdx.x, q = blockIdx.x;
  if (tid < NSTAT) stc[tid] = stats[tid];
  float uvacc = 0.f;
  for (int d = 0; d < DD; ++d) uvacc += qf[(size_t)q * DD + d] * W1[d * H1 + tid];
  __syncthreads();
#pragma unroll
  for (int r = 0; r < CP; ++r)
    h1[r][tid] = fmaxf(stc[1 + CP + r] * uvacc + B1c[r * H1 + tid], 0.f);
  __syncthreads();
  int sg = tid >> 5, kq = tid & 31, k4 = kq * 4, cb = sg * 3;
  float a[3][4];
#pragma unroll
  for (int i = 0; i < 3; ++i)
#pragma unroll
    for (int kk = 0; kk < 4; ++kk) a[i][kk] = 0.f;
  const float4* W2v = (const float4*)W2;
#pragma unroll 2
  for (int j0 = 0; j0 < H1; j0 += 4) {
    float wv[4][4]; float4 hh[3];
#pragma unroll
    for (int jj = 0; jj < 4; ++jj) {
      float4 tv = W2v[(j0 + jj) * 32 + kq];
      wv[jj][0] = tv.x; wv[jj][1] = tv.y; wv[jj][2] = tv.z; wv[jj][3] = tv.w;
    }
#pragma unroll
    for (int i = 0; i < 3; ++i) hh[i] = *(const float4*)&h1[cb + i][j0];
#pragma unroll
    for (int i = 0; i < 3; ++i)
#pragma unroll
      for (int jj = 0; jj < 4; ++jj) {
        float h = ((const float*)&hh[i])[jj];
#pragma unroll
        for (int kk = 0; kk < 4; ++kk) a[i][kk] = fmaf(h, wv[jj][kk], a[i][kk]);
      }
  }
  {
    __align__(16) float part[4] = {0.f, 0.f, 0.f, 0.f};
#pragma unroll
    for (int i = 0; i < 3; ++i) {
      int c = cb + i;
      float gam = stc[1 + 3 * CP + c];
#pragma unroll
      for (int kk = 0; kk < 4; ++kk) part[kk] += gam * a[i][kk];
      if (c < CC) {
        float bet = stc[1 + 2 * CP + c];
        float4 pv = *(const float4*)&pre_ck[c * H2 + k4];
        float4 pr;
        pr.x = fmaxf(pv.x + bet * a[i][0], 0.f);
        pr.y = fmaxf(pv.y + bet * a[i][1], 0.f);
        pr.z = fmaxf(pv.z + bet * a[i][2], 0.f);
        pr.w = fmaxf(pv.w + bet * a[i][3], 0.f);
        *(float4*)&proto[c][k4] = pr;
      }
    }
    *(float4*)&psum[sg][k4] = *(const float4*)part;
  }
  __syncthreads();
  if (tid < H2) {
    float s = 0.f;
#pragma unroll
    for (int g = 0; g < 8; ++g) s += psum[g][tid];
    qel[tid] = fmaxf(stc[0] * s + b2[tid], 0.f);
  }
  __syncthreads();
  if (tid < 160) {
    int c = tid >> 3, ln = tid & 7;
    float num = 0.f, pn = 0.f, qnn = 0.f;
#pragma unroll
    for (int i = 0; i < 16; ++i) {
      int k = ln + 8 * i;
      float e = qel[k], p = proto[c][k];
      num = fmaf(e, p, num); pn = fmaf(p, p, pn); qnn = fmaf(e, e, qnn);
    }
    num += __shfl_xor(num, 1); pn += __shfl_xor(pn, 1); qnn += __shfl_xor(qnn, 1);
    num += __shfl_xor(num, 2); pn += __shfl_xor(pn, 2); qnn += __shfl_xor(qnn, 2);
    num += __shfl_xor(num, 4); pn += __shfl_xor(pn, 4); qnn += __shfl_xor(qnn, 4);
    if (ln == 0)
      out[(size_t)q * CC + c] = num / fmaxf(sqrtf(qnn) * sqrtf(pn), 1e-8f);
  }
}

extern "C" void kernel_launch(void* const* d_in, const int* in_sizes, int n_in,
                              void* d_out, int out_size, void* d_ws, size_t ws_size,
                              hipStream_t stream) {
  const float* Sf     = (const float*)d_in[0];
  const int*   labels = (const int*)d_in[1];
  const float* qf     = (const float*)d_in[2];
  const float* W1     = (const float*)d_in[3];
  const float* b1     = (const float*)d_in[4];
  const float* W2     = (const float*)d_in[5];
  const float* b2     = (const float*)d_in[6];
  int S = in_sizes[1];
  int Q = in_sizes[2] / DD;

  float* ws    = (float*)d_ws;
  float* SumF  = ws + OFF_SUMF;
  float* B1c   = ws + OFF_B1C;
  float* h10   = ws + OFF_H10;
  float* pre   = ws + OFF_PRE;
  float* stats = ws + OFF_ST;
  float* Uptr  = ws + OFF_U;
  float* part  = ws + OFF_U;   // prep partials: dead before k_gemmu writes U
  float* out   = (float*)d_out;

  int totqf = Q * DD;
  int nqf = (totqf + 2047) / 2048;
  size_t off_qb  = OFF_U + (size_t)Q * H1;
  size_t off_w1f = off_qb + (size_t)totqf / 2;
  size_t off_w2f = off_w1f + 65536;
  size_t req     = (off_w2f + 16384) * sizeof(float);
  unsigned short* qb  = (unsigned short*)(ws + off_qb);
  unsigned short* w1f = (unsigned short*)(ws + off_w1f);
  unsigned short* w2f = (unsigned short*)(ws + off_w2f);

  bool fast = ws_size >= req;

  if (fast) {
    k_conv<<<dim3(CC + 1 + nqf + 64 + 16), dim3(256), 0, stream>>>(
        Sf, labels, S, SumF, stats, qf, W1, W2, qb, w1f, w2f, totqf, nqf);
    k_p2a<<<dim3(CC * NDC), dim3(256), 0, stream>>>(SumF, W1, part);
    k_p2r<<<dim3(CC + 1), dim3(256), 0, stream>>>(part, b1, stats, B1c, h10);
    k_pre2<<<dim3(1), dim3(256), 0, stream>>>(h10, W2, b2, stats, pre);
    int mb = (Q + 63) / 64;
    k_gemmu<<<dim3(mb * 4), dim3(256), 0, stream>>>(qb, w1f, Uptr, Q);
    k_fused<<<dim3((Q + QPB - 1) / QPB), dim3(256), 0, stream>>>(
        Uptr, B1c, pre, stats, b2, w2f, out, Q);
  } else {
    k_conv<<<dim3(CC + 1), dim3(256), 0, stream>>>(
        Sf, labels, S, SumF, stats, qf, W1, W2, qb, w1f, w2f, 0, 0);
    k_p2a<<<dim3(CC * NDC), dim3(256), 0, stream>>>(SumF, W1, part);
    k_p2r<<<dim3(CC + 1), dim3(256), 0, stream>>>(part, b1, stats, B1c, h10);
    k_pre2<<<dim3(1), dim3(256), 0, stream>>>(h10, W2, b2, stats, pre);
    k_fb<<<dim3(Q), dim3(256), 0, stream>>>(qf, W1, W2, b2, B1c, pre, stats, out, Q);
  }
}

// Round 6
// 42.891 us; speedup vs baseline: 4.5026x; 1.2614x over previous
//
#include <hip/hip_runtime.h>

#define DD 512   // feature dim
#define H1 256   // hidden 1
#define H2 128   // hidden 2
#define CC 20    // real classes
#define CP 24    // padded classes
#define QPB 4    // queries per block in k_fused
#define MROWS (QPB*CP)   // 96 h1 rows per block
#define PSTR 132         // Pmat row stride (floats)
#define NDC 4            // d-chunks for split-K prep (fallback path)
#define DCH (DD/NDC)     // 128

typedef short v8s __attribute__((ext_vector_type(8)));
typedef float v4f __attribute__((ext_vector_type(4)));

// ---- static ws float offsets ----
#define OFF_SUMF 0
#define OFF_B1C  10240
#define OFF_H10  16384
#define OFF_PRE  16640
#define OFF_ST   19200
#define NSTAT    97
#define OFF_U    19328   // (Qr+64)*H1 floats fast path; also prep partials in fallback

static __device__ __forceinline__ unsigned short f2b(float f) {
  union { float f; unsigned int u; } v; v.f = f;
  unsigned int r = v.u + 0x7FFFu + ((v.u >> 16) & 1u);
  return (unsigned short)(r >> 16);
}

// ================= k_conv: class sums (f32 + bf16 row), stats, bf16/frag conversions ====
__global__ __launch_bounds__(256) void k_conv(
    const float* __restrict__ Sf, const int* __restrict__ labels, int S,
    float* __restrict__ SumF, float* __restrict__ stats,
    const float* __restrict__ qf, const float* __restrict__ W1,
    const float* __restrict__ W2,
    unsigned short* __restrict__ qb, unsigned short* __restrict__ w1f,
    unsigned short* __restrict__ w2f, int totqf, int nqf, int Qr) {
  int b = blockIdx.x, t = threadIdx.x;
  if (b < CC) {
    __shared__ int lab[128];
    if (t < S && t < 128) lab[t] = labels[t];
    __syncthreads();
    for (int d = t; d < DD; d += 256) {
      float acc = 0.f;
      for (int j = 0; j < S; ++j)
        if (lab[j] == b) acc += Sf[j * DD + d];
      SumF[b * DD + d] = acc;
      if (totqf > 0) qb[(size_t)(Qr + b) * DD + d] = f2b(acc);  // class row for MFMA
    }
  } else if (b == CC) {
    if (t < CP) {
      int cnt = 0;
      for (int j = 0; j < S; ++j) if (labels[j] == t) cnt++;
      float deg  = 1.f + (float)cnt;
      float dis  = rsqrtf(deg + 1e-6f);
      float dis0 = rsqrtf((float)S + 1e-6f);
      stats[1 + t]          = dis;
      stats[1 + CP + t]     = dis0 * dis;               // alpha
      stats[1 + 2*CP + t]   = dis * dis * (float)cnt;   // beta (0 pad)
      stats[1 + 3*CP + t]   = dis * (float)cnt;         // gamma (0 pad)
      if (t == 0) stats[0] = dis0;
    }
  } else if (b < CC + 1 + nqf) {
    int idx = (b - CC - 1) * 2048 + t * 8;
    if (idx + 7 < totqf) {
      float4 a = *(const float4*)&qf[idx];
      float4 c = *(const float4*)&qf[idx + 4];
      __align__(16) unsigned short o[8];
      o[0]=f2b(a.x); o[1]=f2b(a.y); o[2]=f2b(a.z); o[3]=f2b(a.w);
      o[4]=f2b(c.x); o[5]=f2b(c.y); o[6]=f2b(c.z); o[7]=f2b(c.w);
      *(v8s*)&qb[idx] = *(const v8s*)o;
    } else {
      for (int e = 0; e < 8; ++e) if (idx + e < totqf) qb[idx + e] = f2b(qf[idx + e]);
    }
  } else if (b < CC + 1 + nqf + 64) {
    int frag = (b - CC - 1 - nqf) * 4 + (t >> 6);
    int l = t & 63, lr = l & 15, lg = l >> 4;
    int nt = frag >> 4, ks = frag & 15;
    __align__(16) unsigned short o[8];
#pragma unroll
    for (int e = 0; e < 8; ++e)
      o[e] = f2b(W1[(ks * 32 + lg * 8 + e) * H1 + nt * 16 + lr]);
    *(v8s*)&w1f[frag * 512 + l * 8] = *(const v8s*)o;
  } else {
    int frag = (b - CC - 1 - nqf - 64) * 4 + (t >> 6);
    int l = t & 63, lr = l & 15, lg = l >> 4;
    int nt = frag >> 3, ks = frag & 7;
    __align__(16) unsigned short o[8];
#pragma unroll
    for (int e = 0; e < 8; ++e)
      o[e] = f2b(W2[(ks * 32 + lg * 8 + e) * H2 + nt * 16 + lr]);
    *(v8s*)&w2f[frag * 512 + l * 8] = *(const v8s*)o;
  }
}

// ================= k_gemmu: Ue = [qf; SumF]_bf16 @ W1_bf16 (MFMA), M rows ==========
__global__ __launch_bounds__(256) void k_gemmu(
    const unsigned short* __restrict__ qb, const unsigned short* __restrict__ w1f,
    float* __restrict__ U, int M) {
  int bm = blockIdx.x >> 2, bn = blockIdx.x & 3;
  int t = threadIdx.x, w = t >> 6, l = t & 63;
  int mh = w >> 1, nh = w & 1;
  int m0 = bm * 64 + mh * 32, n0 = bn * 64 + nh * 32;
  int lr = l & 15, lg = l >> 4;
  v4f acc[2][2];
#pragma unroll
  for (int i = 0; i < 2; ++i)
#pragma unroll
    for (int j = 0; j < 2; ++j) acc[i][j] = (v4f){0.f, 0.f, 0.f, 0.f};
  int r0 = m0 + lr;
  int r1 = m0 + 16 + lr;
  int ntg = bn * 4 + nh * 2;
#pragma unroll 2
  for (int ks = 0; ks < 16; ++ks) {
    const v8s a0 = *(const v8s*)(qb + (size_t)r0 * DD + ks * 32 + lg * 8);
    const v8s a1 = *(const v8s*)(qb + (size_t)r1 * DD + ks * 32 + lg * 8);
    const v8s b0 = *(const v8s*)(w1f + ((ntg * 16 + ks) * 512 + l * 8));
    const v8s b1 = *(const v8s*)(w1f + (((ntg + 1) * 16 + ks) * 512 + l * 8));
    acc[0][0] = __builtin_amdgcn_mfma_f32_16x16x32_bf16(a0, b0, acc[0][0], 0, 0, 0);
    acc[0][1] = __builtin_amdgcn_mfma_f32_16x16x32_bf16(a0, b1, acc[0][1], 0, 0, 0);
    acc[1][0] = __builtin_amdgcn_mfma_f32_16x16x32_bf16(a1, b0, acc[1][0], 0, 0, 0);
    acc[1][1] = __builtin_amdgcn_mfma_f32_16x16x32_bf16(a1, b1, acc[1][1], 0, 0, 0);
  }
#pragma unroll
  for (int mt = 0; mt < 2; ++mt)
#pragma unroll
    for (int nt = 0; nt < 2; ++nt)
#pragma unroll
      for (int r = 0; r < 4; ++r)
        U[(size_t)(m0 + mt * 16 + lg * 4 + r) * H1 + n0 + nt * 16 + lr] = acc[mt][nt][r];
}

// ================= k_fused: 4 queries/block; derives B1c/h10/g2 from Ue class rows ======
__global__ __launch_bounds__(256) void k_fused(
    const float* __restrict__ U, const float* __restrict__ stats,
    const float* __restrict__ b1, const float* __restrict__ b2,
    const float* __restrict__ W2, const unsigned short* __restrict__ w2f,
    float* __restrict__ out, int Q, int Qr) {
  __shared__ float smem[MROWS * PSTR];
  __shared__ float us[QPB * H1];
  __shared__ float qe[QPB * H2];
  __shared__ float qn[QPB];
  __shared__ float stc[NSTAT];
  __shared__ __align__(16) float b1l[H1];
  __shared__ float b2l[H2];
  __shared__ float g2v[H2];
  __shared__ float h10l[H1];
  __shared__ float red[256];
  unsigned short* hb = (unsigned short*)smem;
  float* Pm = smem;

  int t = threadIdx.x, q0 = blockIdx.x * QPB;
  if (t < NSTAT) stc[t] = stats[t];
  b1l[t] = b1[t];
  if (t < H2) b2l[t] = b2[t];
#pragma unroll
  for (int i = 0; i < 4; ++i) {
    int idx = t + 256 * i, r = idx >> 8;
    us[idx] = (q0 + r < Q) ? U[(size_t)(q0 + r) * H1 + (idx & 255)] : 0.f;
  }
  __syncthreads();

  // h10[j] = relu(b1[j] + dis0 * sum_c dis_c * Ue_c[j])
  {
    float s = 0.f;
#pragma unroll
    for (int c = 0; c < CC; ++c)
      s = fmaf(stc[1 + c], U[(size_t)(Qr + c) * H1 + t], s);
    h10l[t] = fmaxf(fmaf(stc[0], s, b1l[t]), 0.f);
  }

  // h1 build (bf16, XOR-swizzled): h1 = relu(alpha_c*u + b1 + dis_c^2*Ue_c)
#pragma unroll 4
  for (int i = 0; i < 12; ++i) {
    int ch = t + 256 * i;
    int r = ch >> 5, jc = ch & 31;
    int q = r / 24, c = r - q * 24;
    float al = stc[1 + CP + c];
    float dc = stc[1 + c], sc = dc * dc;
    int j0 = jc * 8;
    const float4 u0 = *(const float4*)&us[q * H1 + j0];
    const float4 u1 = *(const float4*)&us[q * H1 + j0 + 4];
    const float4 e0 = *(const float4*)&U[(size_t)(Qr + c) * H1 + j0];
    const float4 e1 = *(const float4*)&U[(size_t)(Qr + c) * H1 + j0 + 4];
    const float4 g0 = *(const float4*)&b1l[j0];
    const float4 g1 = *(const float4*)&b1l[j0 + 4];
    __align__(16) unsigned short o[8];
    o[0] = f2b(fmaxf(fmaf(al, u0.x, fmaf(sc, e0.x, g0.x)), 0.f));
    o[1] = f2b(fmaxf(fmaf(al, u0.y, fmaf(sc, e0.y, g0.y)), 0.f));
    o[2] = f2b(fmaxf(fmaf(al, u0.z, fmaf(sc, e0.z, g0.z)), 0.f));
    o[3] = f2b(fmaxf(fmaf(al, u0.w, fmaf(sc, e0.w, g0.w)), 0.f));
    o[4] = f2b(fmaxf(fmaf(al, u1.x, fmaf(sc, e1.x, g1.x)), 0.f));
    o[5] = f2b(fmaxf(fmaf(al, u1.y, fmaf(sc, e1.y, g1.y)), 0.f));
    o[6] = f2b(fmaxf(fmaf(al, u1.z, fmaf(sc, e1.z, g1.z)), 0.f));
    o[7] = f2b(fmaxf(fmaf(al, u1.w, fmaf(sc, e1.w, g1.w)), 0.f));
    int uidx = (r * 256 + j0) ^ ((r & 7) << 3);
    *(v8s*)&hb[uidx] = *(const v8s*)o;
  }
  __syncthreads();

  // g2[k] = h10 @ W2 (j-split x2 + LDS reduce)
  {
    int k = t & 127, jh = t >> 7;
    float g = 0.f;
#pragma unroll 8
    for (int j = jh * 128; j < jh * 128 + 128; ++j)
      g = fmaf(h10l[j], W2[j * H2 + k], g);
    red[t] = g;
  }
  __syncthreads();
  if (t < H2) g2v[t] = red[t] + red[t + 128];   // consumed after post-MFMA barrier

  // MFMA: wave w owns N-tiles {2w, 2w+1}; 6 M-tiles x 8 k-steps
  int w = t >> 6, l = t & 63, lr = l & 15, lg = l >> 4;
  v4f acc[6][2];
#pragma unroll
  for (int mt = 0; mt < 6; ++mt) {
    acc[mt][0] = (v4f){0.f, 0.f, 0.f, 0.f};
    acc[mt][1] = (v4f){0.f, 0.f, 0.f, 0.f};
  }
#pragma unroll
  for (int ks = 0; ks < 8; ++ks) {
    const v8s bb0 = *(const v8s*)(w2f + (((w * 2 + 0) * 8 + ks) * 512 + l * 8));
    const v8s bb1 = *(const v8s*)(w2f + (((w * 2 + 1) * 8 + ks) * 512 + l * 8));
#pragma unroll
    for (int mt = 0; mt < 6; ++mt) {
      int row = mt * 16 + lr;
      const v8s a = *(const v8s*)&hb[(row * 256 + ks * 32 + lg * 8) ^ ((row & 7) << 3)];
      acc[mt][0] = __builtin_amdgcn_mfma_f32_16x16x32_bf16(a, bb0, acc[mt][0], 0, 0, 0);
      acc[mt][1] = __builtin_amdgcn_mfma_f32_16x16x32_bf16(a, bb1, acc[mt][1], 0, 0, 0);
    }
  }
  __syncthreads();   // all hb reads done -> alias as Pmat

#pragma unroll
  for (int mt = 0; mt < 6; ++mt)
#pragma unroll
    for (int nt = 0; nt < 2; ++nt)
#pragma unroll
      for (int r = 0; r < 4; ++r)
        Pm[(mt * 16 + lg * 4 + r) * PSTR + (w * 2 + nt) * 16 + lr] = acc[mt][nt][r];
  __syncthreads();

#pragma unroll
  for (int rep = 0; rep < 2; ++rep) {
    int q = (t >> 7) + rep * 2, k = t & 127;
    float s = 0.f;
#pragma unroll
    for (int c = 0; c < CC; ++c) s = fmaf(stc[1 + 3 * CP + c], Pm[(q * 24 + c) * PSTR + k], s);
    qe[q * H2 + k] = fmaxf(fmaf(stc[0], s, b2l[k]), 0.f);
  }
  __syncthreads();

  if (t < 128) {
    int q = t >> 5, ln = t & 31;
    float s = 0.f;
#pragma unroll
    for (int i = 0; i < 4; ++i) { float e = qe[q * H2 + ln + 32 * i]; s = fmaf(e, e, s); }
    s += __shfl_xor(s, 1); s += __shfl_xor(s, 2); s += __shfl_xor(s, 4);
    s += __shfl_xor(s, 8); s += __shfl_xor(s, 16);
    if (ln == 0) qn[q] = s;
  }
  __syncthreads();

#pragma unroll
  for (int rep = 0; rep < 2; ++rep) {
    int q = (t >> 7) + rep * 2;
    int sub = t & 127, c = sub >> 2, lcl = sub & 3;
    if (c < CC && q0 + q < Q) {
      float num = 0.f, pn = 0.f;
      int rowb = (q * 24 + c) * PSTR;
      float bet = stc[1 + 2 * CP + c];
      float d0dc = stc[0] * stc[1 + c];
#pragma unroll
      for (int i = 0; i < 32; ++i) {
        int k = lcl + 4 * i;
        float P = Pm[rowb + k];
        float pr = fmaxf(fmaf(bet, P, fmaf(d0dc, g2v[k], b2l[k])), 0.f);
        float e = qe[q * H2 + k];
        num = fmaf(e, pr, num); pn = fmaf(pr, pr, pn);
      }
      num += __shfl_xor(num, 1); pn += __shfl_xor(pn, 1);
      num += __shfl_xor(num, 2); pn += __shfl_xor(pn, 2);
      if (lcl == 0)
        out[(size_t)(q0 + q) * CC + c] = num / fmaxf(sqrtf(qn[q]) * sqrtf(pn), 1e-8f);
    }
  }
}

// ================= fallback path kernels (ws too small) =================
__global__ __launch_bounds__(256) void k_p2a(
    const float* __restrict__ SumF, const float* __restrict__ W1,
    float* __restrict__ part) {
  int c = blockIdx.x >> 2, dc = blockIdx.x & 3;
  int n = threadIdx.x;
  int d0 = dc * DCH;
  const float* __restrict__ A  = SumF + c * DD + d0;
  const float* __restrict__ Wp = W1 + (size_t)d0 * H1 + n;
  float acc = 0.f;
#pragma unroll 8
  for (int d = 0; d < DCH; ++d)
    acc = fmaf(A[d], Wp[(size_t)d * H1], acc);
  part[(c * NDC + dc) * H1 + n] = acc;
}

__global__ __launch_bounds__(256) void k_p2r(
    const float* __restrict__ part, const float* __restrict__ b1,
    const float* __restrict__ stats, float* __restrict__ B1c,
    float* __restrict__ h10) {
  int b = blockIdx.x, n = threadIdx.x;
  if (b < CC) {
    float dot = part[(b * NDC + 0) * H1 + n] + part[(b * NDC + 1) * H1 + n]
              + part[(b * NDC + 2) * H1 + n] + part[(b * NDC + 3) * H1 + n];
    float dis = stats[1 + b];
    B1c[b * H1 + n] = fmaf(dis * dis, dot, b1[n]);
  } else {
#pragma unroll
    for (int c = CC; c < CP; ++c) B1c[c * H1 + n] = 0.f;
    float s = 0.f;
#pragma unroll 4
    for (int c = 0; c < CC; ++c) {
      float dot = part[(c * NDC + 0) * H1 + n] + part[(c * NDC + 1) * H1 + n]
                + part[(c * NDC + 2) * H1 + n] + part[(c * NDC + 3) * H1 + n];
      s = fmaf(stats[1 + c], dot, s);
    }
    h10[n] = fmaxf(fmaf(stats[0], s, b1[n]), 0.f);
  }
}

__global__ __launch_bounds__(256) void k_pre2(
    const float* __restrict__ h10, const float* __restrict__ W2,
    const float* __restrict__ b2, const float* __restrict__ stats,
    float* __restrict__ pre) {
  __shared__ float red[256];
  int t = threadIdx.x, k = t & 127, jh = t >> 7;
  float g = 0.f;
#pragma unroll 8
  for (int j = jh * 128; j < jh * 128 + 128; ++j)
    g = fmaf(h10[j], W2[j * H2 + k], g);
  red[t] = g;
  __syncthreads();
  if (t < 128) {
    g = red[t] + red[t + 128];
    float d0 = stats[0], bb = b2[k];
#pragma unroll
    for (int c = 0; c < CC; ++c)
      pre[c * H2 + k] = fmaf(d0 * stats[1 + c], g, bb);
  }
}

__global__ __launch_bounds__(256) void k_fb(
    const float* __restrict__ qf, const float* __restrict__ W1,
    const float* __restrict__ W2, const float* __restrict__ b2,
    const float* __restrict__ B1c, const float* __restrict__ pre_ck,
    const float* __restrict__ stats, float* __restrict__ out, int Q) {
  __shared__ __align__(16) float h1[CP][H1];
  __shared__ __align__(16) float proto[CC][H2 + 4];
  __shared__ __align__(16) float psum[8][H2];
  __shared__ float qel[H2];
  __shared__ float stc[NSTAT];
  int tid = threadIdx.x, q = blockIdx.x;
  if (tid < NSTAT) stc[tid] = stats[tid];
  float uvacc = 0.f;
  for (int d = 0; d < DD; ++d) uvacc += qf[(size_t)q * DD + d] * W1[d * H1 + tid];
  __syncthreads();
#pragma unroll
  for (int r = 0; r < CP; ++r)
    h1[r][tid] = fmaxf(stc[1 + CP + r] * uvacc + B1c[r * H1 + tid], 0.f);
  __syncthreads();
  int sg = tid >> 5, kq = tid & 31, k4 = kq * 4, cb = sg * 3;
  float a[3][4];
#pragma unroll
  for (int i = 0; i < 3; ++i)
#pragma unroll
    for (int kk = 0; kk < 4; ++kk) a[i][kk] = 0.f;
  const float4* W2v = (const float4*)W2;
#pragma unroll 2
  for (int j0 = 0; j0 < H1; j0 += 4) {
    float wv[4][4]; float4 hh[3];
#pragma unroll
    for (int jj = 0; jj < 4; ++jj) {
      float4 tv = W2v[(j0 + jj) * 32 + kq];
      wv[jj][0] = tv.x; wv[jj][1] = tv.y; wv[jj][2] = tv.z; wv[jj][3] = tv.w;
    }
#pragma unroll
    for (int i = 0; i < 3; ++i) hh[i] = *(const float4*)&h1[cb + i][j0];
#pragma unroll
    for (int i = 0; i < 3; ++i)
#pragma unroll
      for (int jj = 0; jj < 4; ++jj) {
        float h = ((const float*)&hh[i])[jj];
#pragma unroll
        for (int kk = 0; kk < 4; ++kk) a[i][kk] = fmaf(h, wv[jj][kk], a[i][kk]);
      }
  }
  {
    __align__(16) float part[4] = {0.f, 0.f, 0.f, 0.f};
#pragma unroll
    for (int i = 0; i < 3; ++i) {
      int c = cb + i;
      float gam = stc[1 + 3 * CP + c];
#pragma unroll
      for (int kk = 0; kk < 4; ++kk) part[kk] += gam * a[i][kk];
      if (c < CC) {
        float bet = stc[1 + 2 * CP + c];
        float4 pv = *(const float4*)&pre_ck[c * H2 + k4];
        float4 pr;
        pr.x = fmaxf(pv.x + bet * a[i][0], 0.f);
        pr.y = fmaxf(pv.y + bet * a[i][1], 0.f);
        pr.z = fmaxf(pv.z + bet * a[i][2], 0.f);
        pr.w = fmaxf(pv.w + bet * a[i][3], 0.f);
        *(float4*)&proto[c][k4] = pr;
      }
    }
    *(float4*)&psum[sg][k4] = *(const float4*)part;
  }
  __syncthreads();
  if (tid < H2) {
    float s = 0.f;
#pragma unroll
    for (int g = 0; g < 8; ++g) s += psum[g][tid];
    qel[tid] = fmaxf(stc[0] * s + b2[tid], 0.f);
  }
  __syncthreads();
  if (tid < 160) {
    int c = tid >> 3, ln = tid & 7;
    float num = 0.f, pn = 0.f, qnn = 0.f;
#pragma unroll
    for (int i = 0; i < 16; ++i) {
      int k = ln + 8 * i;
      float e = qel[k], p = proto[c][k];
      num = fmaf(e, p, num); pn = fmaf(p, p, pn); qnn = fmaf(e, e, qnn);
    }
    num += __shfl_xor(num, 1); pn += __shfl_xor(pn, 1); qnn += __shfl_xor(qnn, 1);
    num += __shfl_xor(num, 2); pn += __shfl_xor(pn, 2); qnn += __shfl_xor(qnn, 2);
    num += __shfl_xor(num, 4); pn += __shfl_xor(pn, 4); qnn += __shfl_xor(qnn, 4);
    if (ln == 0)
      out[(size_t)q * CC + c] = num / fmaxf(sqrtf(qnn) * sqrtf(pn), 1e-8f);
  }
}

extern "C" void kernel_launch(void* const* d_in, const int* in_sizes, int n_in,
                              void* d_out, int out_size, void* d_ws, size_t ws_size,
                              hipStream_t stream) {
  const float* Sf     = (const float*)d_in[0];
  const int*   labels = (const int*)d_in[1];
  const float* qf     = (const float*)d_in[2];
  const float* W1     = (const float*)d_in[3];
  const float* b1     = (const float*)d_in[4];
  const float* W2     = (const float*)d_in[5];
  const float* b2     = (const float*)d_in[6];
  int S = in_sizes[1];
  int Q = in_sizes[2] / DD;

  float* ws    = (float*)d_ws;
  float* SumF  = ws + OFF_SUMF;
  float* B1c   = ws + OFF_B1C;
  float* h10   = ws + OFF_H10;
  float* pre   = ws + OFF_PRE;
  float* stats = ws + OFF_ST;
  float* Uptr  = ws + OFF_U;
  float* part  = ws + OFF_U;   // fallback prep partials
  float* out   = (float*)d_out;

  int Qr = ((Q + 63) / 64) * 64;
  int M  = Qr + 64;            // queries + one extra M-tile holding class-sum rows
  int totqf = Q * DD;
  int nqf = (totqf + 2047) / 2048;
  size_t off_qb  = OFF_U + (size_t)M * H1;       // U floats
  size_t off_w1f = off_qb + (size_t)M * DD / 2;  // qb bf16 (M rows)
  size_t off_w2f = off_w1f + 65536;
  size_t req     = (off_w2f + 16384) * sizeof(float);
  unsigned short* qb  = (unsigned short*)(ws + off_qb);
  unsigned short* w1f = (unsigned short*)(ws + off_w1f);
  unsigned short* w2f = (unsigned short*)(ws + off_w2f);

  bool fast = ws_size >= req;

  if (fast) {
    k_conv<<<dim3(CC + 1 + nqf + 64 + 16), dim3(256), 0, stream>>>(
        Sf, labels, S, SumF, stats, qf, W1, W2, qb, w1f, w2f, totqf, nqf, Qr);
    k_gemmu<<<dim3((M / 64) * 4), dim3(256), 0, stream>>>(qb, w1f, Uptr, M);
    k_fused<<<dim3((Q + QPB - 1) / QPB), dim3(256), 0, stream>>>(
        Uptr, stats, b1, b2, W2, w2f, out, Q, Qr);
  } else {
    k_conv<<<dim3(CC + 1), dim3(256), 0, stream>>>(
        Sf, labels, S, SumF, stats, qf, W1, W2, qb, w1f, w2f, 0, 0, Qr);
    k_p2a<<<dim3(CC * NDC), dim3(256), 0, stream>>>(SumF, W1, part);
    k_p2r<<<dim3(CC + 1), dim3(256), 0, stream>>>(part, b1, stats, B1c, h10);
    k_pre2<<<dim3(1), dim3(256), 0, stream>>>(h10, W2, b2, stats, pre);
    k_fb<<<dim3(Q), dim3(256), 0, stream>>>(qf, W1, W2, b2, B1c, pre, stats, out, Q);
  }
}